// Round 9
// baseline (237.215 us; speedup 1.0000x reference)
//
#include <hip/hip_runtime.h>
#include <math.h>

typedef float v2f __attribute__((ext_vector_type(2)));
typedef unsigned int u32;
typedef _Float16 f16x2 __attribute__((ext_vector_type(2)));

#define LT(i,j) ((i)*((i)+1)/2 + (j))

constexpr int W = 512, H = 512, HW = W * H;
constexpr int PXU = 48;   // u32 words per V pixel (96 f16 channels, 192 B)

__device__ __forceinline__ int reflect512(int i) {
  int a = (i < 0) ? -i : i;
  int b = 1022 - a;
  return (a < b) ? a : b;
}

union HU { u32 u; f16x2 h; };
static __device__ __forceinline__ f16x2 asH(u32 u) { HU x; x.u = u; return x.h; }
static __device__ __forceinline__ u32 pkrtz(float a, float b) {
  union { decltype(__builtin_amdgcn_cvt_pkrtz(0.f, 0.f)) h; u32 u; } x;
  x.h = __builtin_amdgcn_cvt_pkrtz(a, b);
  return x.u;
}
static __device__ __forceinline__ float fdot2(f16x2 a, f16x2 b, float c) {
  return __builtin_amdgcn_fdot2(a, b, c, false);
}

// ---------------- Kernel A: vertical sliding product-sums -> f16 V ----------
// Channels (Z = [x0..x5,y0..y5]): word t<21: (Z2a*Z2b, Z2a+1*Z2b+1) for
// t=LT(a,b); word 21+t: (Z2a*Z2b+1, Z2a+1*Z2b); words 42..47: (Z2i, Z2i+1).
template <int R, bool ADD>
__device__ __forceinline__ void arow(const float* __restrict__ xb,
                                     const float* __restrict__ yb,
                                     int hrow, int w,
                                     v2f* Sd, v2f* Ss, v2f* zs) {
  const int h = reflect512(hrow);
  const float* px = xb + (size_t)h * W + w;
  const float* py = yb + (size_t)h * W + w;
  v2f z[6];
  #pragma unroll
  for (int c = 0; c < 3; ++c) {
    z[c]     = v2f{px[(2*c) * HW], px[(2*c+1) * HW]};
    z[3 + c] = v2f{py[(2*c) * HW], py[(2*c+1) * HW]};
  }
  #pragma unroll
  for (int q = 0; q < 6; ++q) zs[q] = ADD ? (zs[q] + z[q]) : (zs[q] - z[q]);
  int t = 0;
  #pragma unroll
  for (int a = 0; a < 6; ++a)
    #pragma unroll
    for (int b = 0; b <= a; ++b) {
      const v2f m = ADD ? z[a] : -z[a];
      Sd[t] = __builtin_elementwise_fma(m, z[b], Sd[t]);
      Ss[t] = __builtin_elementwise_fma(m, __builtin_shufflevector(z[b], z[b], 1, 0), Ss[t]);
      ++t;
    }
}

__device__ __forceinline__ void storeV(u32* vp, const v2f* Sd, const v2f* Ss,
                                       const v2f* zs) {
  u32 o[48];
  #pragma unroll
  for (int t = 0; t < 21; ++t) o[t]      = pkrtz(Sd[t].x, Sd[t].y);
  #pragma unroll
  for (int t = 0; t < 21; ++t) o[21 + t] = pkrtz(Ss[t].x, Ss[t].y);
  #pragma unroll
  for (int i = 0; i < 6; ++i)  o[42 + i] = pkrtz(zs[i].x, zs[i].y);
  uint4* q = (uint4*)vp;
  #pragma unroll
  for (int i = 0; i < 12; ++i)
    q[i] = make_uint4(o[4*i], o[4*i+1], o[4*i+2], o[4*i+3]);
}

template <int R>
__device__ __forceinline__ void aslice(const float* __restrict__ xg,
                                       const float* __restrict__ yg,
                                       u32* __restrict__ vbuf,
                                       int z, int b, int ch, int w,
                                       int band_r0, int nrows) {
  constexpr int K = 2 * R + 1;
  const float* xb = xg + (size_t)b * 6 * HW;
  const float* yb = yg + (size_t)b * 6 * HW;
  const int h0 = band_r0 + ch * 8;          // first V output row (absolute)
  v2f Sd[21] = {}, Ss[21] = {}, zs[6] = {};
  #pragma unroll
  for (int dy = 0; dy < K; ++dy)
    arow<R, true>(xb, yb, h0 - R + dy, w, Sd, Ss, zs);
  storeV(vbuf + (((size_t)z * nrows + (ch * 8)) * W + w) * PXU, Sd, Ss, zs);
  #pragma unroll 1
  for (int s = 1; s < 8; ++s) {
    arow<R, true >(xb, yb, h0 + s + R,     w, Sd, Ss, zs);
    arow<R, false>(xb, yb, h0 + s - 1 - R, w, Sd, Ss, zs);
    storeV(vbuf + (((size_t)z * nrows + (ch * 8 + s)) * W + w) * PXU, Sd, Ss, zs);
  }
}

__global__ __launch_bounds__(256, 2)
void kernA(const float* __restrict__ xg, const float* __restrict__ yg,
           u32* __restrict__ vbuf, int band_r0, int nrows) {
  const int id = blockIdx.x * 256 + threadIdx.x;
  const int w  = id & 511;
  const int nchunk = nrows >> 3;
  const int ch = (id >> 9) % nchunk;
  const int z  = id / (512 * nchunk);
  if (z < 2) aslice<2>(xg, yg, vbuf, z, z,     ch, w, band_r0, nrows);
  else       aslice<4>(xg, yg, vbuf, z, z - 2, ch, w, band_r0, nrows);
}

// ---------------- Kernel B: horizontal slide + epilogue ---------------------
__device__ __forceinline__ void loadV(const u32* __restrict__ vrow, int col,
                                      u32* Vv) {
  const uint4* p = (const uint4*)(vrow + (size_t)col * PXU);
  #pragma unroll
  for (int i = 0; i < 12; ++i) {
    const uint4 q = p[i];
    Vv[4*i+0] = q.x; Vv[4*i+1] = q.y; Vv[4*i+2] = q.z; Vv[4*i+3] = q.w;
  }
}

__device__ __forceinline__ float gg96(const float* S, int a, int b) {
  if (a < b) { int t = a; a = b; b = t; }
  const int t  = LT(a >> 1, b >> 1);
  const int pa = a & 1, pb = b & 1;
  if (pa == pb) return S[2*t + pa];
  if (pa == 0)  return S[42 + 2*t];
  return S[43 + 2*t];
}

__device__ __forceinline__ void cholinv6(float* a) {
  #pragma unroll
  for (int j = 0; j < 6; ++j) {
    float d = a[LT(j,j)];
    #pragma unroll
    for (int p = 0; p < j; ++p) d -= a[LT(j,p)] * a[LT(j,p)];
    const float rd = __builtin_amdgcn_rsqf(d);
    a[LT(j,j)] = rd;
    #pragma unroll
    for (int i = j + 1; i < 6; ++i) {
      float s = a[LT(i,j)];
      #pragma unroll
      for (int p = 0; p < j; ++p) s -= a[LT(i,p)] * a[LT(j,p)];
      a[LT(i,j)] = s * rd;
    }
  }
  #pragma unroll
  for (int j = 0; j < 6; ++j) {
    #pragma unroll
    for (int i = j + 1; i < 6; ++i) {
      float s = 0.0f;
      #pragma unroll
      for (int p = j; p < i; ++p) s += a[LT(i,p)] * a[LT(p,j)];
      a[LT(i,j)] = -s * a[LT(i,i)];
    }
  }
}

template <int K>
__device__ __forceinline__ float emit96(const float* S) {
  constexpr float inv_n = 1.0f / (K * K);
  float mx[6], my[6];
  #pragma unroll
  for (int i = 0; i < 6; ++i) { mx[i] = S[84 + i] * inv_n; my[i] = S[90 + i] * inv_n; }
  float ax[21];
  {
    int t = 0;
    #pragma unroll
    for (int i = 0; i < 6; ++i)
      #pragma unroll
      for (int j = 0; j <= i; ++j) {
        const float e = (i == j) ? 1e-6f : 0.0f;
        ax[t] = gg96(S, i, j) * inv_n - mx[i] * mx[j] + e;
        ++t;
      }
  }
  cholinv6(ax);
  float ay[21];
  {
    int t = 0;
    #pragma unroll
    for (int i = 0; i < 6; ++i)
      #pragma unroll
      for (int j = 0; j <= i; ++j) {
        const float e = (i == j) ? 1e-6f : 0.0f;
        ay[t] = gg96(S, 6 + i, 6 + j) * inv_n - my[i] * my[j] + e;
        ++t;
      }
  }
  cholinv6(ay);
  float cxy[36];
  #pragma unroll
  for (int i = 0; i < 6; ++i)
    #pragma unroll
    for (int j = 0; j < 6; ++j)
      cxy[i * 6 + j] = fmaf(-mx[i], my[j], gg96(S, i, 6 + j) * inv_n);
  float sim = 0.0f;
  #pragma unroll
  for (int i = 0; i < 6; ++i) {
    float di = 0.0f;
    #pragma unroll
    for (int j = 0; j <= i; ++j) {
      float inner = 0.0f;
      #pragma unroll
      for (int k = i; k < 6; ++k) inner += cxy[j * 6 + k] * ay[LT(k, i)];
      di += ax[LT(i, j)] * inner;
    }
    sim += fabsf(di);
  }
  return sim * (1.0f / 6.0f);
}

template <int R>
__device__ __forceinline__ void bslice(const u32* __restrict__ vbuf,
                                       float* __restrict__ out,
                                       int z, int b, int ri,
                                       int hl, int wch, int band_r0, int nrows) {
  constexpr int K = 2 * R + 1;
  const int habs = band_r0 + hl;
  const int c0 = wch * 8;
  const u32* vrow = vbuf + ((size_t)z * nrows + hl) * W * PXU;

  float S[96] = {};
  u32 Vn[48], Vo[48];

  const f16x2 c10 = {(_Float16)1.0f, (_Float16)0.0f};
  const f16x2 c01 = {(_Float16)0.0f, (_Float16)1.0f};
  const f16x2 cpm = {(_Float16)1.0f, (_Float16)-1.0f};

  // init window: cols c0-R .. c0+R
  #pragma unroll 1
  for (int dx = 0; dx < K; ++dx) {
    loadV(vrow, reflect512(c0 - R + dx), Vn);
    #pragma unroll
    for (int k = 0; k < 48; ++k) {
      S[2*k]   = fdot2(asH(Vn[k]), c10, S[2*k]);
      S[2*k+1] = fdot2(asH(Vn[k]), c01, S[2*k+1]);
    }
  }
  out[((size_t)((b * H + habs) * W + c0)) * 2 + ri] = emit96<K>(S);

  #pragma unroll 1
  for (int s = 1; s < 8; ++s) {
    loadV(vrow, reflect512(c0 + s + R), Vn);
    loadV(vrow, reflect512(c0 + s - 1 - R), Vo);
    #pragma unroll
    for (int k = 0; k < 48; ++k) {
      // (Vn.lo16, Vo.lo16) and (Vn.hi16, Vo.hi16); fdot2 with (1,-1)
      const u32 P1 = __builtin_amdgcn_perm(Vo[k], Vn[k], 0x05040100u);
      const u32 P2 = __builtin_amdgcn_perm(Vo[k], Vn[k], 0x07060302u);
      S[2*k]   = fdot2(asH(P1), cpm, S[2*k]);
      S[2*k+1] = fdot2(asH(P2), cpm, S[2*k+1]);
    }
    out[((size_t)((b * H + habs) * W + c0 + s)) * 2 + ri] = emit96<K>(S);
  }
}

__global__ __launch_bounds__(256, 2)
void kernB(const u32* __restrict__ vbuf, float* __restrict__ out,
           int band_r0, int nrows) {
  const int id  = blockIdx.x * 256 + threadIdx.x;
  const int wch = id & 63;
  const int hl  = (id >> 6) % nrows;
  const int z   = id / (64 * nrows);
  if (z < 2) bslice<2>(vbuf, out, z, z,     0, hl, wch, band_r0, nrows);
  else       bslice<4>(vbuf, out, z, z - 2, 1, hl, wch, band_r0, nrows);
}

// ---------------------------------------------------------------------------
extern "C" void kernel_launch(void* const* d_in, const int* in_sizes, int n_in,
                              void* d_out, int out_size, void* d_ws, size_t ws_size,
                              hipStream_t stream) {
  const float* x = (const float*)d_in[0];
  const float* y = (const float*)d_in[1];
  float* out = (float*)d_out;
  u32* vbuf  = (u32*)d_ws;

  // Per band row (across all 4 z-slices): 4 * 512 * 192 B = 393216 B.
  const size_t per_row = (size_t)4 * W * PXU * 4;
  int band = 512;
  while (band > 8 && (size_t)band * per_row > ws_size) band >>= 1;

  for (int r0 = 0; r0 < 512; r0 += band) {
    const int nr = band;   // 512 % band == 0
    const int blocksA = (4 * 512 * (nr / 8)) / 256;
    const int blocksB = (4 * nr * 64) / 256;
    kernA<<<dim3(blocksA), dim3(256), 0, stream>>>(x, y, vbuf, r0, nr);
    kernB<<<dim3(blocksB), dim3(256), 0, stream>>>(vbuf, out, r0, nr);
  }
}

// Round 10
// 231.863 us; speedup vs baseline: 1.0231x; 1.0231x over previous
//
#include <hip/hip_runtime.h>
#include <math.h>

typedef float v2f __attribute__((ext_vector_type(2)));
typedef float v4f __attribute__((ext_vector_type(4)));

#define LT(i,j) ((i)*((i)+1)/2 + (j))

// reflect index into [0,512)
__device__ __forceinline__ int reflect512(int i) {
  int a = (i < 0) ? -i : i;
  int b = 1022 - a;
  return (a < b) ? a : b;
}

// ---- halo'd interleaved buffer: zb[b][520][520][12] f32, halo=4, reflected.
// pixel layout: [x0x1][x2x3][x4x5][y0y1][y2y3][y4y5] (3 x 16B)
constexpr int HB  = 520;          // 512 + 2*4 halo
constexpr int PS  = 12;           // words per pixel
constexpr int RS  = HB * PS;      // words per halo row (6240)

__global__ __launch_bounds__(256)
void prep_interleave(const float* __restrict__ xg, const float* __restrict__ yg,
                     float* __restrict__ zb) {
  constexpr int H = 512, W = 512, HW = H * W;
  const int idx = blockIdx.x * 256 + threadIdx.x;
  if (idx >= 2 * HB * HB) return;
  const int b  = idx / (HB * HB);
  const int r2 = idx - b * (HB * HB);
  const int hr = r2 / HB;
  const int wc = r2 - hr * HB;
  const int h = reflect512(hr - 4);
  const int w = reflect512(wc - 4);
  const size_t gp = (size_t)b * 6 * HW + (size_t)h * W + w;
  float xv[6], yv[6];
  #pragma unroll
  for (int c = 0; c < 6; ++c) {
    xv[c] = xg[gp + c * HW];
    yv[c] = yg[gp + c * HW];
  }
  float* o = zb + (size_t)idx * PS;
  v4f p0 = {xv[0], xv[1], xv[2], xv[3]};
  v4f p1 = {xv[4], xv[5], yv[0], yv[1]};
  v4f p2 = {yv[2], yv[3], yv[4], yv[5]};
  *(v4f*)(o + 0) = p0;
  *(v4f*)(o + 4) = p1;
  *(v4f*)(o + 8) = p2;
}

// Gram entry g[a][b] (a>=b) from the 2x2-block pk accumulators.
__device__ __forceinline__ float gget(const v2f* accd, const v2f* accs,
                                      int a, int b) {
  const int t = LT(a >> 1, b >> 1);
  if (((a & 1) == 0) && ((b & 1) == 0)) return accd[t].x;
  if (((a & 1) == 1) && ((b & 1) == 1)) return accd[t].y;
  if ((a & 1) == 0) return accs[t].x;
  return accs[t].y;
}

// Packed-lower SPD 6x6 -> packed-lower L^{-1} in place. Divide/sqrt-free.
__device__ __forceinline__ void cholinv6(float* a) {
  #pragma unroll
  for (int j = 0; j < 6; ++j) {
    float d = a[LT(j,j)];
    #pragma unroll
    for (int p = 0; p < j; ++p) d -= a[LT(j,p)] * a[LT(j,p)];
    const float rd = __builtin_amdgcn_rsqf(d);
    a[LT(j,j)] = rd;
    #pragma unroll
    for (int i = j + 1; i < 6; ++i) {
      float s = a[LT(i,j)];
      #pragma unroll
      for (int p = 0; p < j; ++p) s -= a[LT(i,p)] * a[LT(j,p)];
      a[LT(i,j)] = s * rd;
    }
  }
  #pragma unroll
  for (int j = 0; j < 6; ++j) {
    #pragma unroll
    for (int i = j + 1; i < 6; ++i) {
      float s = 0.0f;
      #pragma unroll
      for (int p = j; p < i; ++p) s += a[LT(i,p)] * a[LT(p,j)];
      a[LT(i,j)] = -s * a[LT(i,i)];
    }
  }
}

__device__ __forceinline__ void px_update(const float* __restrict__ p, bool add,
                                          v2f* zs, v2f* accd, v2f* accs) {
  const v4f l0 = *(const v4f*)(p + 0);
  const v4f l1 = *(const v4f*)(p + 4);
  const v4f l2 = *(const v4f*)(p + 8);
  v2f z[6];
  z[0] = l0.lo; z[1] = l0.hi;
  z[2] = l1.lo; z[3] = l1.hi;
  z[4] = l2.lo; z[5] = l2.hi;
  #pragma unroll
  for (int q = 0; q < 6; ++q) zs[q] = add ? (zs[q] + z[q]) : (zs[q] - z[q]);
  int t = 0;
  #pragma unroll
  for (int Kp = 0; Kp < 6; ++Kp) {
    #pragma unroll
    for (int Pp = 0; Pp <= Kp; ++Pp) {
      const v2f c  = z[Pp];
      const v2f cs = __builtin_shufflevector(c, c, 1, 0);
      const v2f a  = add ? z[Kp] : -z[Kp];
      accd[t] = __builtin_elementwise_fma(a, c,  accd[t]);
      accs[t] = __builtin_elementwise_fma(a, cs, accs[t]);
      ++t;
    }
  }
}

// One full row added (init phase).
template <int K>
__device__ __forceinline__ void row_add(const float* __restrict__ p,
                                        v2f* zs, v2f* accd, v2f* accs) {
  #pragma unroll
  for (int dx = 0; dx < K; ++dx)
    px_update(p + dx * PS, true, zs, accd, accs);
}

// Fused slide step: +entering row, -leaving row, interleaved per dx so the
// unrolled loop keeps 2x the independent loads in flight (latency hiding).
template <int K>
__device__ __forceinline__ void row_pm(const float* __restrict__ pe,
                                       const float* __restrict__ pl,
                                       v2f* zs, v2f* accd, v2f* accs) {
  #pragma unroll
  for (int dx = 0; dx < K; ++dx) {
    px_update(pe + dx * PS, true,  zs, accd, accs);
    px_update(pl + dx * PS, false, zs, accd, accs);
  }
}

template <int K>
__device__ __forceinline__ float emit_sim(const v2f* zs, const v2f* accd,
                                          const v2f* accs) {
  constexpr float inv_n = 1.0f / (K * K);
  float mx[6], my[6];
  #pragma unroll
  for (int i = 0; i < 6; ++i) {
    mx[i] = ((i & 1) ? zs[i >> 1].y : zs[i >> 1].x) * inv_n;
    my[i] = ((i & 1) ? zs[3 + (i >> 1)].y : zs[3 + (i >> 1)].x) * inv_n;
  }
  float ax[21];
  {
    int t = 0;
    #pragma unroll
    for (int i = 0; i < 6; ++i)
      #pragma unroll
      for (int j = 0; j <= i; ++j) {
        const float e = (i == j) ? 1e-6f : 0.0f;
        ax[t] = gget(accd, accs, i, j) * inv_n - mx[i] * mx[j] + e;
        ++t;
      }
  }
  cholinv6(ax);
  float ay[21];
  {
    int t = 0;
    #pragma unroll
    for (int i = 0; i < 6; ++i)
      #pragma unroll
      for (int j = 0; j <= i; ++j) {
        const float e = (i == j) ? 1e-6f : 0.0f;
        ay[t] = gget(accd, accs, 6 + i, 6 + j) * inv_n - my[i] * my[j] + e;
        ++t;
      }
  }
  cholinv6(ay);
  float cxy[36];
  #pragma unroll
  for (int i = 0; i < 6; ++i)
    #pragma unroll
    for (int j = 0; j < 6; ++j)
      cxy[i * 6 + j] = fmaf(-mx[i], my[j], gget(accd, accs, 6 + j, i) * inv_n);
  float sim = 0.0f;
  #pragma unroll
  for (int i = 0; i < 6; ++i) {
    float di = 0.0f;
    #pragma unroll
    for (int j = 0; j <= i; ++j) {
      float inner = 0.0f;
      #pragma unroll
      for (int k = i; k < 6; ++k) inner += cxy[j * 6 + k] * ay[LT(k, i)];
      di += ax[LT(i, j)] * inner;
    }
    sim += fabsf(di);
  }
  return sim * (1.0f / 6.0f);
}

// One radius+batch per z. 16 tx x 16 strips, V outputs per strip.
template <int R, int V>
__device__ __forceinline__ void run(const float* __restrict__ zb,
                                    float* __restrict__ out, int b, int ri) {
  constexpr int K = 2 * R + 1;
  constexpr int H = 512, W = 512;

  const int h0 = blockIdx.y * (16 * V);
  const int w0 = blockIdx.x * 16;
  const int tx = threadIdx.x & 15;
  const int g  = threadIdx.x >> 4;
  const int hbase = h0 + g * V;
  const int wc = w0 + tx;

  // first pixel (leftmost col) of the top window row, in halo coords
  const float* base = zb + (size_t)b * HB * RS
                    + (size_t)(hbase + 4 - R) * RS + (size_t)(wc + 4 - R) * PS;

  v2f zs[6]    = {};
  v2f accd[21] = {};
  v2f accs[21] = {};

  #pragma unroll 1
  for (int dy = 0; dy < K; ++dy)
    row_add<K>(base + dy * RS, zs, accd, accs);

  out[((size_t)((b * H + hbase) * W + wc)) * 2 + ri] =
      emit_sim<K>(zs, accd, accs);

  #pragma unroll 1
  for (int s = 1; s < V; ++s) {
    row_pm<K>(base + (s + 2 * R) * RS,      // entering row
              base + (s - 1)     * RS,      // leaving row
              zs, accd, accs);
    out[((size_t)((b * H + hbase + s) * W + wc)) * 2 + ri] =
        emit_sim<K>(zs, accd, accs);
  }
}

// z in {0,1}: r=2 batch z; z in {2,3}: r=4 batch z-2. No LDS, no barriers.
// V=4: 1024 blocks -> 4 blocks/CU -> 4 waves/SIMD (VGPR capped at 128 by
// launch_bounds min-waves=4).
__global__ __launch_bounds__(256, 4)
void cca_v4(const float* __restrict__ zb, float* __restrict__ out) {
  const int z = blockIdx.z;
  if (z < 2) run<2, 4>(zb, out, z, 0);
  else       run<4, 4>(zb, out, z - 2, 1);
}

extern "C" void kernel_launch(void* const* d_in, const int* in_sizes, int n_in,
                              void* d_out, int out_size, void* d_ws, size_t ws_size,
                              hipStream_t stream) {
  const float* x = (const float*)d_in[0];
  const float* y = (const float*)d_in[1];
  float* out = (float*)d_out;
  float* zb  = (float*)d_ws;   // needs 2*520*520*12*4 B = 25.96 MB

  {
    const int n = 2 * HB * HB;
    prep_interleave<<<dim3((n + 255) / 256), dim3(256), 0, stream>>>(x, y, zb);
  }
  dim3 grid(512 / 16, 512 / (16 * 4), 4);   // 32 x 8 x 4 = 1024 blocks
  cca_v4<<<grid, dim3(256), 0, stream>>>(zb, out);
}

// Round 11
// 194.364 us; speedup vs baseline: 1.2205x; 1.1929x over previous
//
#include <hip/hip_runtime.h>
#include <math.h>

typedef float v2f __attribute__((ext_vector_type(2)));
typedef float v4f __attribute__((ext_vector_type(4)));

#define LT(i,j) ((i)*((i)+1)/2 + (j))

// reflect index into [0,512)
__device__ __forceinline__ int reflect512(int i) {
  int a = (i < 0) ? -i : i;
  int b = 1022 - a;
  return (a < b) ? a : b;
}

// ---- halo'd interleaved buffer: zb[b][520][520][12] f32, halo=4, reflected.
// pixel layout: [x0x1][x2x3][x4x5][y0y1][y2y3][y4y5] (3 x 16B)
constexpr int HB  = 520;          // 512 + 2*4 halo
constexpr int PS  = 12;           // words per pixel
constexpr int RS  = HB * PS;      // words per halo row (6240)

__global__ __launch_bounds__(256)
void prep_interleave(const float* __restrict__ xg, const float* __restrict__ yg,
                     float* __restrict__ zb) {
  constexpr int H = 512, W = 512, HW = H * W;
  const int idx = blockIdx.x * 256 + threadIdx.x;
  if (idx >= 2 * HB * HB) return;
  const int b  = idx / (HB * HB);
  const int r2 = idx - b * (HB * HB);
  const int hr = r2 / HB;
  const int wc = r2 - hr * HB;
  const int h = reflect512(hr - 4);
  const int w = reflect512(wc - 4);
  const size_t gp = (size_t)b * 6 * HW + (size_t)h * W + w;
  float xv[6], yv[6];
  #pragma unroll
  for (int c = 0; c < 6; ++c) {
    xv[c] = xg[gp + c * HW];
    yv[c] = yg[gp + c * HW];
  }
  float* o = zb + (size_t)idx * PS;
  v4f p0 = {xv[0], xv[1], xv[2], xv[3]};
  v4f p1 = {xv[4], xv[5], yv[0], yv[1]};
  v4f p2 = {yv[2], yv[3], yv[4], yv[5]};
  *(v4f*)(o + 0) = p0;
  *(v4f*)(o + 4) = p1;
  *(v4f*)(o + 8) = p2;
}

// Gram entry g[a][b] (a>=b) from the 2x2-block pk accumulators.
__device__ __forceinline__ float gget(const v2f* accd, const v2f* accs,
                                      int a, int b) {
  const int t = LT(a >> 1, b >> 1);
  if (((a & 1) == 0) && ((b & 1) == 0)) return accd[t].x;
  if (((a & 1) == 1) && ((b & 1) == 1)) return accd[t].y;
  if ((a & 1) == 0) return accs[t].x;
  return accs[t].y;
}

// Packed-lower SPD 6x6 -> packed-lower L^{-1} in place. Divide/sqrt-free.
__device__ __forceinline__ void cholinv6(float* a) {
  #pragma unroll
  for (int j = 0; j < 6; ++j) {
    float d = a[LT(j,j)];
    #pragma unroll
    for (int p = 0; p < j; ++p) d -= a[LT(j,p)] * a[LT(j,p)];
    const float rd = __builtin_amdgcn_rsqf(d);
    a[LT(j,j)] = rd;
    #pragma unroll
    for (int i = j + 1; i < 6; ++i) {
      float s = a[LT(i,j)];
      #pragma unroll
      for (int p = 0; p < j; ++p) s -= a[LT(i,p)] * a[LT(j,p)];
      a[LT(i,j)] = s * rd;
    }
  }
  #pragma unroll
  for (int j = 0; j < 6; ++j) {
    #pragma unroll
    for (int i = j + 1; i < 6; ++i) {
      float s = 0.0f;
      #pragma unroll
      for (int p = j; p < i; ++p) s += a[LT(i,p)] * a[LT(p,j)];
      a[LT(i,j)] = -s * a[LT(i,i)];
    }
  }
}

__device__ __forceinline__ void px_update(const float* __restrict__ p, bool add,
                                          v2f* zs, v2f* accd, v2f* accs) {
  const v4f l0 = *(const v4f*)(p + 0);
  const v4f l1 = *(const v4f*)(p + 4);
  const v4f l2 = *(const v4f*)(p + 8);
  v2f z[6];
  z[0] = l0.lo; z[1] = l0.hi;
  z[2] = l1.lo; z[3] = l1.hi;
  z[4] = l2.lo; z[5] = l2.hi;
  #pragma unroll
  for (int q = 0; q < 6; ++q) zs[q] = add ? (zs[q] + z[q]) : (zs[q] - z[q]);
  int t = 0;
  #pragma unroll
  for (int Kp = 0; Kp < 6; ++Kp) {
    #pragma unroll
    for (int Pp = 0; Pp <= Kp; ++Pp) {
      const v2f c  = z[Pp];
      const v2f cs = __builtin_shufflevector(c, c, 1, 0);
      const v2f a  = add ? z[Kp] : -z[Kp];
      accd[t] = __builtin_elementwise_fma(a, c,  accd[t]);
      accs[t] = __builtin_elementwise_fma(a, cs, accs[t]);
      ++t;
    }
  }
}

// One full row added (init phase).
template <int K>
__device__ __forceinline__ void row_add(const float* __restrict__ p,
                                        v2f* zs, v2f* accd, v2f* accs) {
  #pragma unroll
  for (int dx = 0; dx < K; ++dx)
    px_update(p + dx * PS, true, zs, accd, accs);
}

// Fused slide step: +entering row, -leaving row, interleaved per dx so the
// unrolled loop keeps 2x the independent loads in flight (latency hiding).
template <int K>
__device__ __forceinline__ void row_pm(const float* __restrict__ pe,
                                       const float* __restrict__ pl,
                                       v2f* zs, v2f* accd, v2f* accs) {
  #pragma unroll
  for (int dx = 0; dx < K; ++dx) {
    px_update(pe + dx * PS, true,  zs, accd, accs);
    px_update(pl + dx * PS, false, zs, accd, accs);
  }
}

template <int K>
__device__ __forceinline__ float emit_sim(const v2f* zs, const v2f* accd,
                                          const v2f* accs) {
  constexpr float inv_n = 1.0f / (K * K);
  float mx[6], my[6];
  #pragma unroll
  for (int i = 0; i < 6; ++i) {
    mx[i] = ((i & 1) ? zs[i >> 1].y : zs[i >> 1].x) * inv_n;
    my[i] = ((i & 1) ? zs[3 + (i >> 1)].y : zs[3 + (i >> 1)].x) * inv_n;
  }
  float ax[21];
  {
    int t = 0;
    #pragma unroll
    for (int i = 0; i < 6; ++i)
      #pragma unroll
      for (int j = 0; j <= i; ++j) {
        const float e = (i == j) ? 1e-6f : 0.0f;
        ax[t] = gget(accd, accs, i, j) * inv_n - mx[i] * mx[j] + e;
        ++t;
      }
  }
  cholinv6(ax);
  float ay[21];
  {
    int t = 0;
    #pragma unroll
    for (int i = 0; i < 6; ++i)
      #pragma unroll
      for (int j = 0; j <= i; ++j) {
        const float e = (i == j) ? 1e-6f : 0.0f;
        ay[t] = gget(accd, accs, 6 + i, 6 + j) * inv_n - my[i] * my[j] + e;
        ++t;
      }
  }
  cholinv6(ay);
  float cxy[36];
  #pragma unroll
  for (int i = 0; i < 6; ++i)
    #pragma unroll
    for (int j = 0; j < 6; ++j)
      cxy[i * 6 + j] = fmaf(-mx[i], my[j], gget(accd, accs, 6 + j, i) * inv_n);
  float sim = 0.0f;
  #pragma unroll
  for (int i = 0; i < 6; ++i) {
    float di = 0.0f;
    #pragma unroll
    for (int j = 0; j <= i; ++j) {
      float inner = 0.0f;
      #pragma unroll
      for (int k = i; k < 6; ++k) inner += cxy[j * 6 + k] * ay[LT(k, i)];
      di += ax[LT(i, j)] * inner;
    }
    sim += fabsf(di);
  }
  return sim * (1.0f / 6.0f);
}

// One radius+batch per z. 16 tx x 16 strips, V outputs per strip.
template <int R, int V>
__device__ __forceinline__ void run(const float* __restrict__ zb,
                                    float* __restrict__ out, int b, int ri) {
  constexpr int K = 2 * R + 1;
  constexpr int H = 512, W = 512;

  const int h0 = blockIdx.y * (16 * V);
  const int w0 = blockIdx.x * 16;
  const int tx = threadIdx.x & 15;
  const int g  = threadIdx.x >> 4;
  const int hbase = h0 + g * V;
  const int wc = w0 + tx;

  // first pixel (leftmost col) of the top window row, in halo coords
  const float* base = zb + (size_t)b * HB * RS
                    + (size_t)(hbase + 4 - R) * RS + (size_t)(wc + 4 - R) * PS;

  v2f zs[6]    = {};
  v2f accd[21] = {};
  v2f accs[21] = {};

  #pragma unroll 1
  for (int dy = 0; dy < K; ++dy)
    row_add<K>(base + dy * RS, zs, accd, accs);

  out[((size_t)((b * H + hbase) * W + wc)) * 2 + ri] =
      emit_sim<K>(zs, accd, accs);

  #pragma unroll 1
  for (int s = 1; s < V; ++s) {
    row_pm<K>(base + (s + 2 * R) * RS,      // entering row
              base + (s - 1)     * RS,      // leaving row
              zs, accd, accs);
    out[((size_t)((b * H + hbase + s) * W + wc)) * 2 + ri] =
        emit_sim<K>(zs, accd, accs);
  }
}

// z in {0,1}: r=2 batch z; z in {2,3}: r=4 batch z-2. No LDS, no barriers.
// V=4: 1024 blocks, 4096 waves -> 3 waves/SIMD resident (bounds(256,3):
// VGPR cap ~168 >= ~150 live set; (256,4) made the compiler crush to 64
// VGPRs and spill 347 MB -- R10).
__global__ __launch_bounds__(256, 3)
void cca_v4(const float* __restrict__ zb, float* __restrict__ out) {
  const int z = blockIdx.z;
  if (z < 2) run<2, 4>(zb, out, z, 0);
  else       run<4, 4>(zb, out, z - 2, 1);
}

extern "C" void kernel_launch(void* const* d_in, const int* in_sizes, int n_in,
                              void* d_out, int out_size, void* d_ws, size_t ws_size,
                              hipStream_t stream) {
  const float* x = (const float*)d_in[0];
  const float* y = (const float*)d_in[1];
  float* out = (float*)d_out;
  float* zb  = (float*)d_ws;   // needs 2*520*520*12*4 B = 25.96 MB

  {
    const int n = 2 * HB * HB;
    prep_interleave<<<dim3((n + 255) / 256), dim3(256), 0, stream>>>(x, y, zb);
  }
  dim3 grid(512 / 16, 512 / (16 * 4), 4);   // 32 x 8 x 4 = 1024 blocks
  cca_v4<<<grid, dim3(256), 0, stream>>>(zb, out);
}

// Round 12
// 155.536 us; speedup vs baseline: 1.5251x; 1.2496x over previous
//
#include <hip/hip_runtime.h>
#include <math.h>

typedef float v2f __attribute__((ext_vector_type(2)));
typedef float v4f __attribute__((ext_vector_type(4)));

#define LT(i,j) ((i)*((i)+1)/2 + (j))

// reflect index into [0,512)
__device__ __forceinline__ int reflect512(int i) {
  int a = (i < 0) ? -i : i;
  int b = 1022 - a;
  return (a < b) ? a : b;
}

// ---- halo'd interleaved buffer: zb[b][520][520][12] f32, halo=4, reflected.
// pixel layout: [x0x1][x2x3][x4x5][y0y1][y2y3][y4y5] (3 x 16B)
constexpr int HB  = 520;          // 512 + 2*4 halo
constexpr int PS  = 12;           // words per pixel
constexpr int RS  = HB * PS;      // words per halo row (6240)

__global__ __launch_bounds__(256)
void prep_interleave(const float* __restrict__ xg, const float* __restrict__ yg,
                     float* __restrict__ zb) {
  constexpr int H = 512, W = 512, HW = H * W;
  const int idx = blockIdx.x * 256 + threadIdx.x;
  if (idx >= 2 * HB * HB) return;
  const int b  = idx / (HB * HB);
  const int r2 = idx - b * (HB * HB);
  const int hr = r2 / HB;
  const int wc = r2 - hr * HB;
  const int h = reflect512(hr - 4);
  const int w = reflect512(wc - 4);
  const size_t gp = (size_t)b * 6 * HW + (size_t)h * W + w;
  float xv[6], yv[6];
  #pragma unroll
  for (int c = 0; c < 6; ++c) {
    xv[c] = xg[gp + c * HW];
    yv[c] = yg[gp + c * HW];
  }
  float* o = zb + (size_t)idx * PS;
  v4f p0 = {xv[0], xv[1], xv[2], xv[3]};
  v4f p1 = {xv[4], xv[5], yv[0], yv[1]};
  v4f p2 = {yv[2], yv[3], yv[4], yv[5]};
  *(v4f*)(o + 0) = p0;
  *(v4f*)(o + 4) = p1;
  *(v4f*)(o + 8) = p2;
}

// Gram entry g[a][b] (a>=b) from the 2x2-block pk accumulators.
__device__ __forceinline__ float gget(const v2f* accd, const v2f* accs,
                                      int a, int b) {
  const int t = LT(a >> 1, b >> 1);
  if (((a & 1) == 0) && ((b & 1) == 0)) return accd[t].x;
  if (((a & 1) == 1) && ((b & 1) == 1)) return accd[t].y;
  if ((a & 1) == 0) return accs[t].x;
  return accs[t].y;
}

// Packed-lower SPD 6x6 -> packed-lower L^{-1} in place. Divide/sqrt-free.
__device__ __forceinline__ void cholinv6(float* a) {
  #pragma unroll
  for (int j = 0; j < 6; ++j) {
    float d = a[LT(j,j)];
    #pragma unroll
    for (int p = 0; p < j; ++p) d -= a[LT(j,p)] * a[LT(j,p)];
    const float rd = __builtin_amdgcn_rsqf(d);
    a[LT(j,j)] = rd;
    #pragma unroll
    for (int i = j + 1; i < 6; ++i) {
      float s = a[LT(i,j)];
      #pragma unroll
      for (int p = 0; p < j; ++p) s -= a[LT(i,p)] * a[LT(j,p)];
      a[LT(i,j)] = s * rd;
    }
  }
  #pragma unroll
  for (int j = 0; j < 6; ++j) {
    #pragma unroll
    for (int i = j + 1; i < 6; ++i) {
      float s = 0.0f;
      #pragma unroll
      for (int p = j; p < i; ++p) s += a[LT(i,p)] * a[LT(p,j)];
      a[LT(i,j)] = -s * a[LT(i,i)];
    }
  }
}

__device__ __forceinline__ void px_update(const float* __restrict__ p, bool add,
                                          v2f* zs, v2f* accd, v2f* accs) {
  const v4f l0 = *(const v4f*)(p + 0);
  const v4f l1 = *(const v4f*)(p + 4);
  const v4f l2 = *(const v4f*)(p + 8);
  v2f z[6];
  z[0] = l0.lo; z[1] = l0.hi;
  z[2] = l1.lo; z[3] = l1.hi;
  z[4] = l2.lo; z[5] = l2.hi;
  #pragma unroll
  for (int q = 0; q < 6; ++q) zs[q] = add ? (zs[q] + z[q]) : (zs[q] - z[q]);
  int t = 0;
  #pragma unroll
  for (int Kp = 0; Kp < 6; ++Kp) {
    #pragma unroll
    for (int Pp = 0; Pp <= Kp; ++Pp) {
      const v2f c  = z[Pp];
      const v2f cs = __builtin_shufflevector(c, c, 1, 0);
      const v2f a  = add ? z[Kp] : -z[Kp];
      accd[t] = __builtin_elementwise_fma(a, c,  accd[t]);
      accs[t] = __builtin_elementwise_fma(a, cs, accs[t]);
      ++t;
    }
  }
}

// One full row added (init phase).
template <int K>
__device__ __forceinline__ void row_add(const float* __restrict__ p,
                                        v2f* zs, v2f* accd, v2f* accs) {
  #pragma unroll
  for (int dx = 0; dx < K; ++dx)
    px_update(p + dx * PS, true, zs, accd, accs);
}

// Fused slide step: +entering row, -leaving row, interleaved per dx so the
// unrolled loop keeps 2x the independent loads in flight (latency hiding).
template <int K>
__device__ __forceinline__ void row_pm(const float* __restrict__ pe,
                                       const float* __restrict__ pl,
                                       v2f* zs, v2f* accd, v2f* accs) {
  #pragma unroll
  for (int dx = 0; dx < K; ++dx) {
    px_update(pe + dx * PS, true,  zs, accd, accs);
    px_update(pl + dx * PS, false, zs, accd, accs);
  }
}

template <int K>
__device__ __forceinline__ float emit_sim(const v2f* zs, const v2f* accd,
                                          const v2f* accs) {
  constexpr float inv_n = 1.0f / (K * K);
  float mx[6], my[6];
  #pragma unroll
  for (int i = 0; i < 6; ++i) {
    mx[i] = ((i & 1) ? zs[i >> 1].y : zs[i >> 1].x) * inv_n;
    my[i] = ((i & 1) ? zs[3 + (i >> 1)].y : zs[3 + (i >> 1)].x) * inv_n;
  }
  float ax[21];
  {
    int t = 0;
    #pragma unroll
    for (int i = 0; i < 6; ++i)
      #pragma unroll
      for (int j = 0; j <= i; ++j) {
        const float e = (i == j) ? 1e-6f : 0.0f;
        ax[t] = gget(accd, accs, i, j) * inv_n - mx[i] * mx[j] + e;
        ++t;
      }
  }
  cholinv6(ax);
  float ay[21];
  {
    int t = 0;
    #pragma unroll
    for (int i = 0; i < 6; ++i)
      #pragma unroll
      for (int j = 0; j <= i; ++j) {
        const float e = (i == j) ? 1e-6f : 0.0f;
        ay[t] = gget(accd, accs, 6 + i, 6 + j) * inv_n - my[i] * my[j] + e;
        ++t;
      }
  }
  cholinv6(ay);
  float cxy[36];
  #pragma unroll
  for (int i = 0; i < 6; ++i)
    #pragma unroll
    for (int j = 0; j < 6; ++j)
      cxy[i * 6 + j] = fmaf(-mx[i], my[j], gget(accd, accs, 6 + j, i) * inv_n);
  float sim = 0.0f;
  #pragma unroll
  for (int i = 0; i < 6; ++i) {
    float di = 0.0f;
    #pragma unroll
    for (int j = 0; j <= i; ++j) {
      float inner = 0.0f;
      #pragma unroll
      for (int k = i; k < 6; ++k) inner += cxy[j * 6 + k] * ay[LT(k, i)];
      di += ax[LT(i, j)] * inner;
    }
    sim += fabsf(di);
  }
  return sim * (1.0f / 6.0f);
}

// One radius+batch per z. 16 tx x 16 strips, V outputs per strip.
template <int R, int V>
__device__ __forceinline__ void run(const float* __restrict__ zb,
                                    float* __restrict__ out, int b, int ri) {
  constexpr int K = 2 * R + 1;
  constexpr int H = 512, W = 512;

  const int h0 = blockIdx.y * (16 * V);
  const int w0 = blockIdx.x * 16;
  const int tx = threadIdx.x & 15;
  const int g  = threadIdx.x >> 4;
  const int hbase = h0 + g * V;
  const int wc = w0 + tx;

  // first pixel (leftmost col) of the top window row, in halo coords
  const float* base = zb + (size_t)b * HB * RS
                    + (size_t)(hbase + 4 - R) * RS + (size_t)(wc + 4 - R) * PS;

  v2f zs[6]    = {};
  v2f accd[21] = {};
  v2f accs[21] = {};

  #pragma unroll 1
  for (int dy = 0; dy < K; ++dy)
    row_add<K>(base + dy * RS, zs, accd, accs);

  out[((size_t)((b * H + hbase) * W + wc)) * 2 + ri] =
      emit_sim<K>(zs, accd, accs);

  #pragma unroll 1
  for (int s = 1; s < V; ++s) {
    row_pm<K>(base + (s + 2 * R) * RS,      // entering row
              base + (s - 1)     * RS,      // leaving row
              zs, accd, accs);
    out[((size_t)((b * H + hbase + s) * W + wc)) * 2 + ri] =
        emit_sim<K>(zs, accd, accs);
  }
}

// z in {0,1}: r=2 batch z; z in {2,3}: r=4 batch z-2. No LDS, no barriers.
// V=4: 1024 blocks, 4096 waves -> 4 waves/SIMD resident.
// NOTE bounds MUST stay (256,2): this compiler maps min-waves=3 -> 84 VGPR
// (R11) and =4 -> 64 VGPR (R10), both catastrophic spill. (256,2) reliably
// yields VGPR=128 with zero spill (R5/R8), and 4 waves x 128 = 512 fits the
// SIMD register file exactly.
__global__ __launch_bounds__(256, 2)
void cca_v4(const float* __restrict__ zb, float* __restrict__ out) {
  const int z = blockIdx.z;
  if (z < 2) run<2, 4>(zb, out, z, 0);
  else       run<4, 4>(zb, out, z - 2, 1);
}

extern "C" void kernel_launch(void* const* d_in, const int* in_sizes, int n_in,
                              void* d_out, int out_size, void* d_ws, size_t ws_size,
                              hipStream_t stream) {
  const float* x = (const float*)d_in[0];
  const float* y = (const float*)d_in[1];
  float* out = (float*)d_out;
  float* zb  = (float*)d_ws;   // needs 2*520*520*12*4 B = 25.96 MB

  {
    const int n = 2 * HB * HB;
    prep_interleave<<<dim3((n + 255) / 256), dim3(256), 0, stream>>>(x, y, zb);
  }
  dim3 grid(512 / 16, 512 / (16 * 4), 4);   // 32 x 8 x 4 = 1024 blocks
  cca_v4<<<grid, dim3(256), 0, stream>>>(zb, out);
}

// Round 13
// 149.612 us; speedup vs baseline: 1.5855x; 1.0396x over previous
//
#include <hip/hip_runtime.h>
#include <math.h>

typedef float v2f __attribute__((ext_vector_type(2)));
typedef float v4f __attribute__((ext_vector_type(4)));

#define LT(i,j) ((i)*((i)+1)/2 + (j))
#define OD(A,B) (LT(A,B) - (A))   // off-diagonal block index (A>B), 0..14

// reflect index into [0,512)
__device__ __forceinline__ int reflect512(int i) {
  int a = (i < 0) ? -i : i;
  int b = 1022 - a;
  return (a < b) ? a : b;
}

// ---- halo'd interleaved buffer: zb[b][520][520][12] f32, halo=4, reflected.
// pixel layout: [x0x1][x2x3][x4x5][y0y1][y2y3][y4y5] (3 x 16B)
constexpr int HB  = 520;          // 512 + 2*4 halo
constexpr int PS  = 12;           // words per pixel
constexpr int RS  = HB * PS;      // words per halo row (6240)

// Vectorized prep: each thread fills 4 consecutive halo pixels. Interior
// column-groups (reflected cols contiguous ascending) use b128 plane loads;
// the two edge groups fall back to scalar gathers.
__global__ __launch_bounds__(256)
void prep_interleave4(const float* __restrict__ xg, const float* __restrict__ yg,
                      float* __restrict__ zb) {
  constexpr int H = 512, W = 512, HW = H * W;
  const int idx = blockIdx.x * 256 + threadIdx.x;
  if (idx >= 2 * HB * (HB / 4)) return;
  const int b  = idx / (HB * (HB / 4));
  const int r2 = idx - b * (HB * (HB / 4));
  const int hr = r2 / (HB / 4);
  const int c4 = r2 - hr * (HB / 4);     // column group, 0..129
  const int h  = reflect512(hr - 4);
  const size_t pbase = (size_t)b * 6 * HW + (size_t)h * W;

  float xv[6][4], yv[6][4];
  if (c4 >= 1 && c4 <= 128) {
    // cols 4*c4-4 .. 4*c4-1, contiguous & 16B-aligned
    const int w0 = 4 * c4 - 4;
    #pragma unroll
    for (int c = 0; c < 6; ++c) {
      const v4f xq = *(const v4f*)(xg + pbase + c * HW + w0);
      const v4f yq = *(const v4f*)(yg + pbase + c * HW + w0);
      xv[c][0] = xq.x; xv[c][1] = xq.y; xv[c][2] = xq.z; xv[c][3] = xq.w;
      yv[c][0] = yq.x; yv[c][1] = yq.y; yv[c][2] = yq.z; yv[c][3] = yq.w;
    }
  } else {
    #pragma unroll
    for (int j = 0; j < 4; ++j) {
      const int w = reflect512(4 * c4 + j - 4);
      #pragma unroll
      for (int c = 0; c < 6; ++c) {
        xv[c][j] = xg[pbase + c * HW + w];
        yv[c][j] = yg[pbase + c * HW + w];
      }
    }
  }
  float* o = zb + ((size_t)(b * HB + hr) * HB + 4 * c4) * PS;
  #pragma unroll
  for (int j = 0; j < 4; ++j) {
    v4f p0 = {xv[0][j], xv[1][j], xv[2][j], xv[3][j]};
    v4f p1 = {xv[4][j], xv[5][j], yv[0][j], yv[1][j]};
    v4f p2 = {yv[2][j], yv[3][j], yv[4][j], yv[5][j]};
    *(v4f*)(o + j * PS + 0) = p0;
    *(v4f*)(o + j * PS + 4) = p1;
    *(v4f*)(o + j * PS + 8) = p2;
  }
}

// Gram entry g[a][b] (a>=b). accd: 21 diag-lane blocks; accs: 15 off-diag
// swapped-lane blocks; accm: 6 within-block cross products (lanes were equal,
// so they live as scalars -- saves 6 regs and 6x2 cyc/position).
__device__ __forceinline__ float gget(const v2f* accd, const v2f* accs,
                                      const float* accm, int a, int b) {
  const int A = a >> 1, B = b >> 1;
  const int pa = a & 1, pb = b & 1;
  if (pa == pb) return (pa == 0) ? accd[LT(A, B)].x : accd[LT(A, B)].y;
  if (A == B) return accm[A];
  return (pa == 0) ? accs[OD(A, B)].x : accs[OD(A, B)].y;
}

// Packed-lower SPD 6x6 -> packed-lower L^{-1} in place. Divide/sqrt-free.
__device__ __forceinline__ void cholinv6(float* a) {
  #pragma unroll
  for (int j = 0; j < 6; ++j) {
    float d = a[LT(j,j)];
    #pragma unroll
    for (int p = 0; p < j; ++p) d -= a[LT(j,p)] * a[LT(j,p)];
    const float rd = __builtin_amdgcn_rsqf(d);
    a[LT(j,j)] = rd;
    #pragma unroll
    for (int i = j + 1; i < 6; ++i) {
      float s = a[LT(i,j)];
      #pragma unroll
      for (int p = 0; p < j; ++p) s -= a[LT(i,p)] * a[LT(j,p)];
      a[LT(i,j)] = s * rd;
    }
  }
  #pragma unroll
  for (int j = 0; j < 6; ++j) {
    #pragma unroll
    for (int i = j + 1; i < 6; ++i) {
      float s = 0.0f;
      #pragma unroll
      for (int p = j; p < i; ++p) s += a[LT(i,p)] * a[LT(p,j)];
      a[LT(i,j)] = -s * a[LT(i,i)];
    }
  }
}

__device__ __forceinline__ void px_update(const float* __restrict__ p, bool add,
                                          v2f* zs, v2f* accd, v2f* accs,
                                          float* accm) {
  const v4f l0 = *(const v4f*)(p + 0);
  const v4f l1 = *(const v4f*)(p + 4);
  const v4f l2 = *(const v4f*)(p + 8);
  v2f z[6];
  z[0] = l0.lo; z[1] = l0.hi;
  z[2] = l1.lo; z[3] = l1.hi;
  z[4] = l2.lo; z[5] = l2.hi;
  #pragma unroll
  for (int q = 0; q < 6; ++q) zs[q] = add ? (zs[q] + z[q]) : (zs[q] - z[q]);
  #pragma unroll
  for (int Kp = 0; Kp < 6; ++Kp) {
    const v2f a = add ? z[Kp] : -z[Kp];
    #pragma unroll
    for (int Pp = 0; Pp < Kp; ++Pp) {
      const v2f c = z[Pp];
      accd[LT(Kp, Pp)] = __builtin_elementwise_fma(a, c, accd[LT(Kp, Pp)]);
      accs[OD(Kp, Pp)] = __builtin_elementwise_fma(
          a, __builtin_shufflevector(c, c, 1, 0), accs[OD(Kp, Pp)]);
    }
    accd[LT(Kp, Kp)] = __builtin_elementwise_fma(a, z[Kp], accd[LT(Kp, Kp)]);
    accm[Kp] = fmaf(a.x, z[Kp].y, accm[Kp]);   // scalar: both pk lanes equal
  }
}

// One full row added (init phase).
template <int K>
__device__ __forceinline__ void row_add(const float* __restrict__ p,
                                        v2f* zs, v2f* accd, v2f* accs,
                                        float* accm) {
  #pragma unroll
  for (int dx = 0; dx < K; ++dx)
    px_update(p + dx * PS, true, zs, accd, accs, accm);
}

// Fused slide step: +entering row, -leaving row, interleaved per dx.
template <int K>
__device__ __forceinline__ void row_pm(const float* __restrict__ pe,
                                       const float* __restrict__ pl,
                                       v2f* zs, v2f* accd, v2f* accs,
                                       float* accm) {
  #pragma unroll
  for (int dx = 0; dx < K; ++dx) {
    px_update(pe + dx * PS, true,  zs, accd, accs, accm);
    px_update(pl + dx * PS, false, zs, accd, accs, accm);
  }
}

template <int K>
__device__ __forceinline__ float emit_sim(const v2f* zs, const v2f* accd,
                                          const v2f* accs, const float* accm) {
  constexpr float inv_n = 1.0f / (K * K);
  float mx[6], my[6];
  #pragma unroll
  for (int i = 0; i < 6; ++i) {
    mx[i] = ((i & 1) ? zs[i >> 1].y : zs[i >> 1].x) * inv_n;
    my[i] = ((i & 1) ? zs[3 + (i >> 1)].y : zs[3 + (i >> 1)].x) * inv_n;
  }
  float ax[21];
  {
    int t = 0;
    #pragma unroll
    for (int i = 0; i < 6; ++i)
      #pragma unroll
      for (int j = 0; j <= i; ++j) {
        const float e = (i == j) ? 1e-6f : 0.0f;
        ax[t] = gget(accd, accs, accm, i, j) * inv_n - mx[i] * mx[j] + e;
        ++t;
      }
  }
  cholinv6(ax);
  float ay[21];
  {
    int t = 0;
    #pragma unroll
    for (int i = 0; i < 6; ++i)
      #pragma unroll
      for (int j = 0; j <= i; ++j) {
        const float e = (i == j) ? 1e-6f : 0.0f;
        ay[t] = gget(accd, accs, accm, 6 + i, 6 + j) * inv_n - my[i] * my[j] + e;
        ++t;
      }
  }
  cholinv6(ay);
  float cxy[36];
  #pragma unroll
  for (int i = 0; i < 6; ++i)
    #pragma unroll
    for (int j = 0; j < 6; ++j)
      cxy[i * 6 + j] =
          fmaf(-mx[i], my[j], gget(accd, accs, accm, 6 + j, i) * inv_n);
  float sim = 0.0f;
  #pragma unroll
  for (int i = 0; i < 6; ++i) {
    float di = 0.0f;
    #pragma unroll
    for (int j = 0; j <= i; ++j) {
      float inner = 0.0f;
      #pragma unroll
      for (int k = i; k < 6; ++k) inner += cxy[j * 6 + k] * ay[LT(k, i)];
      di += ax[LT(i, j)] * inner;
    }
    sim += fabsf(di);
  }
  return sim * (1.0f / 6.0f);
}

// One radius+batch per z. 16 tx x 16 strips, V outputs per strip.
template <int R, int V>
__device__ __forceinline__ void run(const float* __restrict__ zb,
                                    float* __restrict__ out, int b, int ri) {
  constexpr int K = 2 * R + 1;
  constexpr int H = 512, W = 512;

  const int h0 = blockIdx.y * (16 * V);
  const int w0 = blockIdx.x * 16;
  const int tx = threadIdx.x & 15;
  const int g  = threadIdx.x >> 4;
  const int hbase = h0 + g * V;
  const int wc = w0 + tx;

  const float* base = zb + (size_t)b * HB * RS
                    + (size_t)(hbase + 4 - R) * RS + (size_t)(wc + 4 - R) * PS;

  v2f zs[6]    = {};
  v2f accd[21] = {};
  v2f accs[15] = {};
  float accm[6] = {};

  #pragma unroll 1
  for (int dy = 0; dy < K; ++dy)
    row_add<K>(base + dy * RS, zs, accd, accs, accm);

  out[((size_t)((b * H + hbase) * W + wc)) * 2 + ri] =
      emit_sim<K>(zs, accd, accs, accm);

  #pragma unroll 1
  for (int s = 1; s < V; ++s) {
    row_pm<K>(base + (s + 2 * R) * RS,      // entering row
              base + (s - 1)     * RS,      // leaving row
              zs, accd, accs, accm);
    out[((size_t)((b * H + hbase + s) * W + wc)) * 2 + ri] =
        emit_sim<K>(zs, accd, accs, accm);
  }
}

// z in {0,1}: r=2 batch z; z in {2,3}: r=4 batch z-2. No LDS, no barriers.
// bounds MUST stay (256,2): min-waves=3 -> 84 VGPR (R11), =4 -> 64 VGPR
// (R10), both catastrophic spill. (256,2) gives VGPR=128, zero spill, and
// V=4's 4096 waves fill 4 waves/SIMD (4 x 128 = 512-reg file exactly).
__global__ __launch_bounds__(256, 2)
void cca_v4(const float* __restrict__ zb, float* __restrict__ out) {
  const int z = blockIdx.z;
  if (z < 2) run<2, 4>(zb, out, z, 0);
  else       run<4, 4>(zb, out, z - 2, 1);
}

extern "C" void kernel_launch(void* const* d_in, const int* in_sizes, int n_in,
                              void* d_out, int out_size, void* d_ws, size_t ws_size,
                              hipStream_t stream) {
  const float* x = (const float*)d_in[0];
  const float* y = (const float*)d_in[1];
  float* out = (float*)d_out;
  float* zb  = (float*)d_ws;   // needs 2*520*520*12*4 B = 25.96 MB

  {
    const int n = 2 * HB * (HB / 4);   // 4 pixels per thread
    prep_interleave4<<<dim3((n + 255) / 256), dim3(256), 0, stream>>>(x, y, zb);
  }
  dim3 grid(512 / 16, 512 / (16 * 4), 4);   // 32 x 8 x 4 = 1024 blocks
  cca_v4<<<grid, dim3(256), 0, stream>>>(zb, out);
}